// Round 5
// baseline (813.165 us; speedup 1.0000x reference)
//
#include <hip/hip_runtime.h>

// Problem constants
static constexpr int P = 16384;           // 128*128 plane

// Workspace layout (float offsets). Total ~43.5 MB.
static constexpr int OFF_H1   = 0;         // 24 planes (post-relu act layer1)
static constexpr int OFF_H2   = 24 * P;    // 24
static constexpr int OFF_H3   = 48 * P;    // 24
static constexpr int OFF_H4   = 72 * P;    // 24
static constexpr int OFF_OUT5 = 96 * P;    // 12 (kappa,v1,v2,f,u_rk[8])
static constexpr int OFF_GA   = 108 * P;   // 11*24 planes (backward ping)
static constexpr int OFF_GB   = 372 * P;   // 11*24 planes (backward pong; also 18-ch input stage)
static constexpr int OFF_DXY  = 636 * P;   // 22 planes: per cot [dx, dy] interleaved
static constexpr int OFF_W    = 658 * P;   // packed weights

// packed weight sub-offsets (relative to OFF_W), layout [tap][cin][cout]
static constexpr int PW1 = 0;        // 25*18*24 = 10800
static constexpr int PW2 = 10800;    // 25*24*24 = 14400
static constexpr int PW3 = 25200;
static constexpr int PW4 = 39600;
static constexpr int PW5 = 54000;    // 25*24*12 = 7200
static constexpr int PB4 = 61200;    // transposed+flipped for backward
static constexpr int PB3 = 75600;
static constexpr int PB2 = 90000;
static constexpr int PB1 = 104400;   // 25*24*2 = 1200

// ---------------------------------------------------------------------------
// Repack weights:
//  forward:  Wp[t][ci][co]  = W[co][ci][t]
//  backward: B [t][co][ci]  = W[co][ci][24-t]   (transpose ci<->co, flip taps)
// ---------------------------------------------------------------------------
__global__ void pack_weights(const float* __restrict__ W1, const float* __restrict__ W2,
                             const float* __restrict__ W3, const float* __restrict__ W4,
                             const float* __restrict__ W5, float* __restrict__ wp) {
    int i = blockIdx.x * 256 + threadIdx.x;
    if (i < 10800) {                       // W1p [25][18][24]
        int co = i % 24, ci = (i / 24) % 18, t = i / 432;
        wp[PW1 + i] = W1[(co * 18 + ci) * 25 + t];
    }
    if (i < 14400) {                       // W2p/W3p/W4p + B4/B3/B2
        int co = i % 24, ci = (i / 24) % 24, t = i / 576;
        wp[PW2 + i] = W2[(co * 24 + ci) * 25 + t];
        wp[PW3 + i] = W3[(co * 24 + ci) * 25 + t];
        wp[PW4 + i] = W4[(co * 24 + ci) * 25 + t];
        // here i = (t*24 + cf_out)*24 + cf_in with cf_in=i%24, cf_out=(i/24)%24
        int cin = i % 24, cout = (i / 24) % 24, tb = i / 576;
        wp[PB4 + i] = W4[(cout * 24 + cin) * 25 + (24 - tb)];
        wp[PB3 + i] = W3[(cout * 24 + cin) * 25 + (24 - tb)];
        wp[PB2 + i] = W2[(cout * 24 + cin) * 25 + (24 - tb)];
    }
    if (i < 7200) {                        // W5p [25][24][12]
        int co = i % 12, ci = (i / 12) % 24, t = i / 288;
        wp[PW5 + i] = W5[(co * 24 + ci) * 25 + t];
    }
    if (i < 1200) {                        // B1 [25][24][2] (only input ch 0,1 needed)
        int ci = i % 2, co = (i / 2) % 24, t = i / 48;
        wp[PB1 + i] = W1[(co * 18 + ci) * 25 + (24 - t)];
    }
}

// Stage x,y,u as a contiguous 18-plane tensor
__global__ void stage_input(const float* __restrict__ x, const float* __restrict__ y,
                            const float* __restrict__ u, float* __restrict__ in18) {
    int i = blockIdx.x * 256 + threadIdx.x;   // 18*P threads
    int pl = i / P, p = i - pl * P;
    float v = (pl == 0) ? x[p] : (pl == 1) ? y[p] : u[(pl - 2) * P + p];
    in18[i] = v;
}

// ---------------------------------------------------------------------------
// Generic 5x5 SAME conv over 128x128 planes.
//  - 16x16 output tile per 256-thread block, halo staged in LDS (row stride 24
//    floats -> 2-way bank aliasing only, which is free on CDNA4).
//  - weights packed [tap][cin][cout]; inner co loop reads contiguous
//    block-uniform addresses -> scalar loads, SGPR operand in v_fmac.
//  - BATCH: blockIdx.z folds (cotangent, channel-half).
//  - MASK: multiply output by (mask_plane > 0) -> relu backward.
// ---------------------------------------------------------------------------
template <int CIN, int COUT_TOT, int COB, bool RELU, bool MASK, bool BATCH>
__global__ __launch_bounds__(256) void conv5x5(
    const float* __restrict__ inbase, const float* __restrict__ wp,
    const float* __restrict__ bias, const float* __restrict__ maskbase,
    float* __restrict__ outbase) {
    constexpr int NSPL = COUT_TOT / COB;
    const int z = blockIdx.z;
    const int half = z % NSPL;
    const int cot = z / NSPL;
    const float* in = inbase + (BATCH ? cot * CIN * P : 0);
    float* out = outbase + (BATCH ? cot * COUT_TOT * P : 0);
    const int cobase = half * COB;

    __shared__ float smem[CIN][20][24];
    const int tid = threadIdx.x;
    const int bx = blockIdx.x, by = blockIdx.y;

    for (int i = tid; i < CIN * 400; i += 256) {
        int ci = i / 400, rem = i - ci * 400;
        int r = rem / 20, c = rem - r * 20;
        int gy = by * 16 + r - 2, gx = bx * 16 + c - 2;
        float v = 0.f;
        if ((unsigned)gy < 128u && (unsigned)gx < 128u) v = in[ci * P + gy * 128 + gx];
        smem[ci][r][c] = v;
    }
    __syncthreads();

    const int ty = tid >> 4, tx = tid & 15;
    float acc[COB];
#pragma unroll
    for (int co = 0; co < COB; ++co) acc[co] = bias ? bias[cobase + co] : 0.f;

    for (int a = 0; a < 5; ++a) {
        for (int b = 0; b < 5; ++b) {
            const float* __restrict__ wrow = wp + ((a * 5 + b) * CIN) * COUT_TOT + cobase;
            for (int ci = 0; ci < CIN; ++ci) {
                float v = smem[ci][ty + a][tx + b];
#pragma unroll
                for (int co = 0; co < COB; ++co)
                    acc[co] = fmaf(v, wrow[ci * COUT_TOT + co], acc[co]);
            }
        }
    }

    const int gy = by * 16 + ty, gx = bx * 16 + tx, gp = gy * 128 + gx;
#pragma unroll
    for (int co = 0; co < COB; ++co) {
        float v = acc[co];
        if (RELU) v = v > 0.f ? v : 0.f;
        if (MASK) v = (maskbase[(cobase + co) * P + gp] > 0.f) ? v : 0.f;
        out[(cobase + co) * P + gp] = v;
    }
}

// ---------------------------------------------------------------------------
// Initial backward cotangent through conv5^T for one-hot-channel, all-ones
// cotangents: g4[j,y,x] = m4[j,y,x] * sum_{a,b valid} W5[oc, j, a, b]
// (valid: 0 <= y-a+2 < 128 and 0 <= x-b+2 < 128). blockIdx.z = cot index.
// ---------------------------------------------------------------------------
__global__ __launch_bounds__(256) void bcot_init(const float* __restrict__ W5,
                                                 const float* __restrict__ h4,
                                                 float* __restrict__ gA) {
    const int i = blockIdx.z;              // 0..10
    const int oc = (i < 3) ? i : i + 1;    // idx = [0,1,2,4..11]
    const int tid = threadIdx.x;
    const int gy = blockIdx.y * 16 + (tid >> 4);
    const int gx = blockIdx.x * 16 + (tid & 15);
    const int gp = gy * 128 + gx;
    float* g = gA + i * 24 * P;
    for (int j = 0; j < 24; ++j) {
        const float* __restrict__ w = W5 + (oc * 24 + j) * 25;
        float s = 0.f;
        for (int a = 0; a < 5; ++a) {
            int yy = gy + 2 - a;
            if ((unsigned)yy >= 128u) continue;
            for (int b = 0; b < 5; ++b) {
                int xx = gx + 2 - b;
                if ((unsigned)xx >= 128u) continue;
                s += w[a * 5 + b];
            }
        }
        g[j * P + gp] = (h4[j * P + gp] > 0.f) ? s : 0.f;
    }
}

// ---------------------------------------------------------------------------
// Finalize: pde[q] = (kappa_x+v1)*u_rk_x[q] + (kappa_y+v2)*u_rk_y[q] + f
// (second-order terms are exactly zero for a ReLU network), then the two
// 8x8 RK einsums and the 26-plane output concat.
// ---------------------------------------------------------------------------
__global__ __launch_bounds__(256) void finalize(const float* __restrict__ ws,
                                                const float* __restrict__ rkA,
                                                const float* __restrict__ rkb,
                                                float* __restrict__ outp) {
    const int p = blockIdx.x * 256 + threadIdx.x;   // 16384 threads
    const float* o5 = ws + OFF_OUT5;
    const float* dxy = ws + OFF_DXY;

    const float kap = o5[0 * P + p], v1 = o5[1 * P + p];
    const float v2  = o5[2 * P + p], f  = o5[3 * P + p];
    const float kx  = dxy[0 * P + p], ky  = dxy[1 * P + p];
    const float v1x = dxy[2 * P + p], v1y = dxy[3 * P + p];
    const float v2x = dxy[4 * P + p], v2y = dxy[5 * P + p];
    const float cx = kx + v1, cy = ky + v2;

    float pde[8], urk[8];
#pragma unroll
    for (int q = 0; q < 8; ++q) {
        urk[q] = o5[(4 + q) * P + p];
        float ux = dxy[(6 + 2 * q) * P + p];
        float uy = dxy[(7 + 2 * q) * P + p];
        pde[q] = fmaf(cx, ux, fmaf(cy, uy, f));
    }
#pragma unroll
    for (int r = 0; r < 8; ++r) {
        float si = 0.f, sf = 0.f;
#pragma unroll
        for (int j = 0; j < 8; ++j) {
            float a = rkA[r * 8 + j];
            si = fmaf(a, pde[j], si);
            sf = fmaf(a - rkb[j], pde[j], sf);
        }
        outp[r * P + p] = urk[r] + si;
        outp[(8 + r) * P + p] = urk[r] + sf;
    }
    outp[16 * P + p] = kap;
    outp[17 * P + p] = kx;
    outp[18 * P + p] = ky;
    outp[19 * P + p] = v1;
    outp[20 * P + p] = v1x;
    outp[21 * P + p] = v1y;
    outp[22 * P + p] = v2;
    outp[23 * P + p] = v2x;
    outp[24 * P + p] = v2y;
    outp[25 * P + p] = f;
}

extern "C" void kernel_launch(void* const* d_in, const int* in_sizes, int n_in,
                              void* d_out, int out_size, void* d_ws, size_t ws_size,
                              hipStream_t stream) {
    const float* x   = (const float*)d_in[0];
    const float* y   = (const float*)d_in[1];
    const float* u   = (const float*)d_in[2];
    const float* W1  = (const float*)d_in[3];
    const float* b1  = (const float*)d_in[4];
    const float* W2  = (const float*)d_in[5];
    const float* b2  = (const float*)d_in[6];
    const float* W3  = (const float*)d_in[7];
    const float* b3  = (const float*)d_in[8];
    const float* W4  = (const float*)d_in[9];
    const float* b4  = (const float*)d_in[10];
    const float* W5  = (const float*)d_in[11];
    const float* b5  = (const float*)d_in[12];
    const float* rkA = (const float*)d_in[13];
    const float* rkb = (const float*)d_in[14];

    float* ws   = (float*)d_ws;
    float* outp = (float*)d_out;
    float* wp   = ws + OFF_W;

    // 1) repack weights + stage 18-channel input (into GB region, free for now)
    pack_weights<<<dim3(57), dim3(256), 0, stream>>>(W1, W2, W3, W4, W5, wp);
    stage_input<<<dim3(18 * 64), dim3(256), 0, stream>>>(x, y, u, ws + OFF_GB);

    // 2) forward net (activations kept for backward relu masks)
    dim3 blk(256);
    conv5x5<18, 24, 12, true, false, false><<<dim3(8, 8, 2), blk, 0, stream>>>(
        ws + OFF_GB, wp + PW1, b1, nullptr, ws + OFF_H1);
    conv5x5<24, 24, 12, true, false, false><<<dim3(8, 8, 2), blk, 0, stream>>>(
        ws + OFF_H1, wp + PW2, b2, nullptr, ws + OFF_H2);
    conv5x5<24, 24, 12, true, false, false><<<dim3(8, 8, 2), blk, 0, stream>>>(
        ws + OFF_H2, wp + PW3, b3, nullptr, ws + OFF_H3);
    conv5x5<24, 24, 12, true, false, false><<<dim3(8, 8, 2), blk, 0, stream>>>(
        ws + OFF_H3, wp + PW4, b4, nullptr, ws + OFF_H4);
    conv5x5<24, 12, 12, false, false, false><<<dim3(8, 8, 1), blk, 0, stream>>>(
        ws + OFF_H4, wp + PW5, b5, nullptr, ws + OFF_OUT5);

    // 3) backward: 11 one-hot cotangents batched in blockIdx.z
    bcot_init<<<dim3(8, 8, 11), blk, 0, stream>>>(W5, ws + OFF_H4, ws + OFF_GA);
    // dL/dz3 = m3 * (W4^T (*) dL/dz4)
    conv5x5<24, 24, 12, false, true, true><<<dim3(8, 8, 22), blk, 0, stream>>>(
        ws + OFF_GA, wp + PB4, nullptr, ws + OFF_H3, ws + OFF_GB);
    // dL/dz2
    conv5x5<24, 24, 12, false, true, true><<<dim3(8, 8, 22), blk, 0, stream>>>(
        ws + OFF_GB, wp + PB3, nullptr, ws + OFF_H2, ws + OFF_GA);
    // dL/dz1
    conv5x5<24, 24, 12, false, true, true><<<dim3(8, 8, 22), blk, 0, stream>>>(
        ws + OFF_GA, wp + PB2, nullptr, ws + OFF_H1, ws + OFF_GB);
    // dL/d(x,y): conv1^T restricted to input channels {0,1}
    conv5x5<24, 2, 2, false, false, true><<<dim3(8, 8, 11), blk, 0, stream>>>(
        ws + OFF_GB, wp + PB1, nullptr, nullptr, ws + OFF_DXY);

    // 4) pointwise PDE + RK combine + output concat (26 planes)
    finalize<<<dim3(64), blk, 0, stream>>>(ws, rkA, rkb, outp);
}

// Round 6
// 600.289 us; speedup vs baseline: 1.3546x; 1.3546x over previous
//
#include <hip/hip_runtime.h>

// Problem constants
static constexpr int P = 16384;           // 128*128 plane

// Workspace layout (float offsets). Total ~43.5 MB.
static constexpr int OFF_H1   = 0;         // 24 planes (post-relu act layer1)
static constexpr int OFF_H2   = 24 * P;    // 24
static constexpr int OFF_H3   = 48 * P;    // 24
static constexpr int OFF_H4   = 72 * P;    // 24
static constexpr int OFF_OUT5 = 96 * P;    // 12 (kappa,v1,v2,f,u_rk[8])
static constexpr int OFF_GA   = 108 * P;   // 11*24 planes (backward ping)
static constexpr int OFF_GB   = 372 * P;   // 11*24 planes (backward pong; also 18-ch input stage)
static constexpr int OFF_DXY  = 636 * P;   // 22 planes: per cot [dx, dy] interleaved
static constexpr int OFF_W    = 658 * P;   // packed weights

// packed weight sub-offsets (relative to OFF_W), layout [tap][cin][cout]
static constexpr int PW1 = 0;        // 25*18*24 = 10800
static constexpr int PW2 = 10800;    // 25*24*24 = 14400
static constexpr int PW3 = 25200;
static constexpr int PW4 = 39600;
static constexpr int PW5 = 54000;    // 25*24*12 = 7200
static constexpr int PB4 = 61200;    // transposed+flipped for backward
static constexpr int PB3 = 75600;
static constexpr int PB2 = 90000;
static constexpr int PB1 = 104400;   // 25*24*2 = 1200

// ---------------------------------------------------------------------------
// Repack weights:
//  forward:  Wp[t][ci][co]  = W[co][ci][t]
//  backward: B [t][co][ci]  = W[co][ci][24-t]   (transpose ci<->co, flip taps)
// ---------------------------------------------------------------------------
__global__ void pack_weights(const float* __restrict__ W1, const float* __restrict__ W2,
                             const float* __restrict__ W3, const float* __restrict__ W4,
                             const float* __restrict__ W5, float* __restrict__ wp) {
    int i = blockIdx.x * 256 + threadIdx.x;
    if (i < 10800) {                       // W1p [25][18][24]
        int co = i % 24, ci = (i / 24) % 18, t = i / 432;
        wp[PW1 + i] = W1[(co * 18 + ci) * 25 + t];
    }
    if (i < 14400) {                       // W2p/W3p/W4p + B4/B3/B2
        int co = i % 24, ci = (i / 24) % 24, t = i / 576;
        wp[PW2 + i] = W2[(co * 24 + ci) * 25 + t];
        wp[PW3 + i] = W3[(co * 24 + ci) * 25 + t];
        wp[PW4 + i] = W4[(co * 24 + ci) * 25 + t];
        // here i = (t*24 + cf_out)*24 + cf_in with cf_in=i%24, cf_out=(i/24)%24
        int cin = i % 24, cout = (i / 24) % 24, tb = i / 576;
        wp[PB4 + i] = W4[(cout * 24 + cin) * 25 + (24 - tb)];
        wp[PB3 + i] = W3[(cout * 24 + cin) * 25 + (24 - tb)];
        wp[PB2 + i] = W2[(cout * 24 + cin) * 25 + (24 - tb)];
    }
    if (i < 7200) {                        // W5p [25][24][12]
        int co = i % 12, ci = (i / 12) % 24, t = i / 288;
        wp[PW5 + i] = W5[(co * 24 + ci) * 25 + t];
    }
    if (i < 1200) {                        // B1 [25][24][2] (only input ch 0,1 needed)
        int ci = i % 2, co = (i / 2) % 24, t = i / 48;
        wp[PB1 + i] = W1[(co * 18 + ci) * 25 + (24 - t)];
    }
}

// Stage x,y,u as a contiguous 18-plane tensor
__global__ void stage_input(const float* __restrict__ x, const float* __restrict__ y,
                            const float* __restrict__ u, float* __restrict__ in18) {
    int i = blockIdx.x * 256 + threadIdx.x;   // 18*P threads
    int pl = i / P, p = i - pl * P;
    float v = (pl == 0) ? x[p] : (pl == 1) ? y[p] : u[(pl - 2) * P + p];
    in18[i] = v;
}

// ---------------------------------------------------------------------------
// Generic 5x5 SAME conv over 128x128 planes.
//  - 16x16 output tile per 256-thread block, halo staged in LDS in CIN-chunks
//    of CHUNK channels (LDS = CHUNK*20*24*4 B; 12 -> 23 KB => ~7 blocks/CU,
//    vs 24 -> 46 KB => 3 blocks/CU which measured 29% occupancy / 33% VALUBusy).
//  - row stride 24 floats -> only 2-way bank aliasing (free on CDNA4).
//  - weights packed [tap][cin][cout]; inner co loop reads contiguous
//    block-uniform addresses -> scalar loads, SGPR operand in v_fmac.
//  - __launch_bounds__(256,7): cap VGPR ~73 so occupancy is LDS-limited.
//  - BATCH: blockIdx.z folds (cotangent, channel-chunk).
//  - MASK: multiply output by (mask_plane > 0) -> relu backward.
// ---------------------------------------------------------------------------
template <int CIN, int CHUNK, int COUT_TOT, int COB, bool RELU, bool MASK, bool BATCH>
__global__ __launch_bounds__(256, 7) void conv5x5(
    const float* __restrict__ inbase, const float* __restrict__ wp,
    const float* __restrict__ bias, const float* __restrict__ maskbase,
    float* __restrict__ outbase) {
    constexpr int NSPL = COUT_TOT / COB;
    const int z = blockIdx.z;
    const int half = z % NSPL;
    const int cot = z / NSPL;
    const float* in = inbase + (BATCH ? cot * CIN * P : 0);
    float* out = outbase + (BATCH ? cot * COUT_TOT * P : 0);
    const int cobase = half * COB;

    __shared__ float smem[CHUNK][20][24];
    const int tid = threadIdx.x;
    const int bx = blockIdx.x, by = blockIdx.y;
    const int ty = tid >> 4, tx = tid & 15;

    float acc[COB];
#pragma unroll
    for (int co = 0; co < COB; ++co) acc[co] = bias ? bias[cobase + co] : 0.f;

    for (int c0 = 0; c0 < CIN; c0 += CHUNK) {
        if (c0) __syncthreads();           // previous chunk's compute must finish
        for (int i = tid; i < CHUNK * 400; i += 256) {
            int ci = i / 400, rem = i - ci * 400;
            int r = rem / 20, c = rem - r * 20;
            int gy = by * 16 + r - 2, gx = bx * 16 + c - 2;
            float v = 0.f;
            if ((unsigned)gy < 128u && (unsigned)gx < 128u)
                v = in[(c0 + ci) * P + gy * 128 + gx];
            smem[ci][r][c] = v;
        }
        __syncthreads();

        for (int a = 0; a < 5; ++a) {
            for (int b = 0; b < 5; ++b) {
                const float* __restrict__ wrow =
                    wp + ((a * 5 + b) * CIN + c0) * COUT_TOT + cobase;
                for (int ci = 0; ci < CHUNK; ++ci) {
                    float v = smem[ci][ty + a][tx + b];
#pragma unroll
                    for (int co = 0; co < COB; ++co)
                        acc[co] = fmaf(v, wrow[ci * COUT_TOT + co], acc[co]);
                }
            }
        }
    }

    const int gy = by * 16 + ty, gx = bx * 16 + tx, gp = gy * 128 + gx;
#pragma unroll
    for (int co = 0; co < COB; ++co) {
        float v = acc[co];
        if (RELU) v = v > 0.f ? v : 0.f;
        if (MASK) v = (maskbase[(cobase + co) * P + gp] > 0.f) ? v : 0.f;
        out[(cobase + co) * P + gp] = v;
    }
}

// ---------------------------------------------------------------------------
// Initial backward cotangent through conv5^T for one-hot-channel, all-ones
// cotangents: g4[j,y,x] = m4[j,y,x] * sum_{a,b valid} W5[oc, j, a, b]
// (valid: 0 <= y-a+2 < 128 and 0 <= x-b+2 < 128). blockIdx.z = cot index.
// ---------------------------------------------------------------------------
__global__ __launch_bounds__(256) void bcot_init(const float* __restrict__ W5,
                                                 const float* __restrict__ h4,
                                                 float* __restrict__ gA) {
    const int i = blockIdx.z;              // 0..10
    const int oc = (i < 3) ? i : i + 1;    // idx = [0,1,2,4..11]
    const int tid = threadIdx.x;
    const int gy = blockIdx.y * 16 + (tid >> 4);
    const int gx = blockIdx.x * 16 + (tid & 15);
    const int gp = gy * 128 + gx;
    float* g = gA + i * 24 * P;
    for (int j = 0; j < 24; ++j) {
        const float* __restrict__ w = W5 + (oc * 24 + j) * 25;
        float s = 0.f;
        for (int a = 0; a < 5; ++a) {
            int yy = gy + 2 - a;
            if ((unsigned)yy >= 128u) continue;
            for (int b = 0; b < 5; ++b) {
                int xx = gx + 2 - b;
                if ((unsigned)xx >= 128u) continue;
                s += w[a * 5 + b];
            }
        }
        g[j * P + gp] = (h4[j * P + gp] > 0.f) ? s : 0.f;
    }
}

// ---------------------------------------------------------------------------
// Finalize: pde[q] = (kappa_x+v1)*u_rk_x[q] + (kappa_y+v2)*u_rk_y[q] + f
// (second-order terms are exactly zero for a ReLU network), then the two
// 8x8 RK einsums and the 26-plane output concat.
// ---------------------------------------------------------------------------
__global__ __launch_bounds__(256) void finalize(const float* __restrict__ ws,
                                                const float* __restrict__ rkA,
                                                const float* __restrict__ rkb,
                                                float* __restrict__ outp) {
    const int p = blockIdx.x * 256 + threadIdx.x;   // 16384 threads
    const float* o5 = ws + OFF_OUT5;
    const float* dxy = ws + OFF_DXY;

    const float kap = o5[0 * P + p], v1 = o5[1 * P + p];
    const float v2  = o5[2 * P + p], f  = o5[3 * P + p];
    const float kx  = dxy[0 * P + p], ky  = dxy[1 * P + p];
    const float v1x = dxy[2 * P + p], v1y = dxy[3 * P + p];
    const float v2x = dxy[4 * P + p], v2y = dxy[5 * P + p];
    const float cx = kx + v1, cy = ky + v2;

    float pde[8], urk[8];
#pragma unroll
    for (int q = 0; q < 8; ++q) {
        urk[q] = o5[(4 + q) * P + p];
        float ux = dxy[(6 + 2 * q) * P + p];
        float uy = dxy[(7 + 2 * q) * P + p];
        pde[q] = fmaf(cx, ux, fmaf(cy, uy, f));
    }
#pragma unroll
    for (int r = 0; r < 8; ++r) {
        float si = 0.f, sf = 0.f;
#pragma unroll
        for (int j = 0; j < 8; ++j) {
            float a = rkA[r * 8 + j];
            si = fmaf(a, pde[j], si);
            sf = fmaf(a - rkb[j], pde[j], sf);
        }
        outp[r * P + p] = urk[r] + si;
        outp[(8 + r) * P + p] = urk[r] + sf;
    }
    outp[16 * P + p] = kap;
    outp[17 * P + p] = kx;
    outp[18 * P + p] = ky;
    outp[19 * P + p] = v1;
    outp[20 * P + p] = v1x;
    outp[21 * P + p] = v1y;
    outp[22 * P + p] = v2;
    outp[23 * P + p] = v2x;
    outp[24 * P + p] = v2y;
    outp[25 * P + p] = f;
}

extern "C" void kernel_launch(void* const* d_in, const int* in_sizes, int n_in,
                              void* d_out, int out_size, void* d_ws, size_t ws_size,
                              hipStream_t stream) {
    const float* x   = (const float*)d_in[0];
    const float* y   = (const float*)d_in[1];
    const float* u   = (const float*)d_in[2];
    const float* W1  = (const float*)d_in[3];
    const float* b1  = (const float*)d_in[4];
    const float* W2  = (const float*)d_in[5];
    const float* b2  = (const float*)d_in[6];
    const float* W3  = (const float*)d_in[7];
    const float* b3  = (const float*)d_in[8];
    const float* W4  = (const float*)d_in[9];
    const float* b4  = (const float*)d_in[10];
    const float* W5  = (const float*)d_in[11];
    const float* b5  = (const float*)d_in[12];
    const float* rkA = (const float*)d_in[13];
    const float* rkb = (const float*)d_in[14];

    float* ws   = (float*)d_ws;
    float* outp = (float*)d_out;
    float* wp   = ws + OFF_W;

    // 1) repack weights + stage 18-channel input (into GB region, free for now)
    pack_weights<<<dim3(57), dim3(256), 0, stream>>>(W1, W2, W3, W4, W5, wp);
    stage_input<<<dim3(18 * 64), dim3(256), 0, stream>>>(x, y, u, ws + OFF_GB);

    // 2) forward net (activations kept for backward relu masks)
    // COB=4 -> z=6 (384 blocks): forward was 128-block TLP-starved at COB=12.
    dim3 blk(256);
    conv5x5<18, 9, 24, 4, true, false, false><<<dim3(8, 8, 6), blk, 0, stream>>>(
        ws + OFF_GB, wp + PW1, b1, nullptr, ws + OFF_H1);
    conv5x5<24, 12, 24, 4, true, false, false><<<dim3(8, 8, 6), blk, 0, stream>>>(
        ws + OFF_H1, wp + PW2, b2, nullptr, ws + OFF_H2);
    conv5x5<24, 12, 24, 4, true, false, false><<<dim3(8, 8, 6), blk, 0, stream>>>(
        ws + OFF_H2, wp + PW3, b3, nullptr, ws + OFF_H3);
    conv5x5<24, 12, 24, 4, true, false, false><<<dim3(8, 8, 6), blk, 0, stream>>>(
        ws + OFF_H3, wp + PW4, b4, nullptr, ws + OFF_H4);
    conv5x5<24, 12, 12, 4, false, false, false><<<dim3(8, 8, 3), blk, 0, stream>>>(
        ws + OFF_H4, wp + PW5, b5, nullptr, ws + OFF_OUT5);

    // 3) backward: 11 one-hot cotangents batched in blockIdx.z
    bcot_init<<<dim3(8, 8, 11), blk, 0, stream>>>(W5, ws + OFF_H4, ws + OFF_GA);
    // dL/dz3 = m3 * (W4^T (*) dL/dz4)
    conv5x5<24, 12, 24, 12, false, true, true><<<dim3(8, 8, 22), blk, 0, stream>>>(
        ws + OFF_GA, wp + PB4, nullptr, ws + OFF_H3, ws + OFF_GB);
    // dL/dz2
    conv5x5<24, 12, 24, 12, false, true, true><<<dim3(8, 8, 22), blk, 0, stream>>>(
        ws + OFF_GB, wp + PB3, nullptr, ws + OFF_H2, ws + OFF_GA);
    // dL/dz1
    conv5x5<24, 12, 24, 12, false, true, true><<<dim3(8, 8, 22), blk, 0, stream>>>(
        ws + OFF_GA, wp + PB2, nullptr, ws + OFF_H1, ws + OFF_GB);
    // dL/d(x,y): conv1^T restricted to input channels {0,1}
    conv5x5<24, 12, 2, 2, false, false, true><<<dim3(8, 8, 11), blk, 0, stream>>>(
        ws + OFF_GB, wp + PB1, nullptr, nullptr, ws + OFF_DXY);

    // 4) pointwise PDE + RK combine + output concat (26 planes)
    finalize<<<dim3(64), blk, 0, stream>>>(ws, rkA, rkb, outp);
}

// Round 7
// 584.825 us; speedup vs baseline: 1.3904x; 1.0264x over previous
//
#include <hip/hip_runtime.h>

// Problem constants
static constexpr int P = 16384;           // 128*128 plane

// Workspace layout (float offsets). Total ~43.5 MB.
static constexpr int OFF_H1   = 0;         // 24 planes (post-relu act layer1)
static constexpr int OFF_H2   = 24 * P;    // 24
static constexpr int OFF_H3   = 48 * P;    // 24
static constexpr int OFF_H4   = 72 * P;    // 24
static constexpr int OFF_OUT5 = 96 * P;    // 12 (kappa,v1,v2,f,u_rk[8])
static constexpr int OFF_GA   = 108 * P;   // backward ping; ALSO holds bcot table (consumed by dz3 before dz2 overwrites)
static constexpr int OFF_GB   = 372 * P;   // backward pong; also 18-ch input stage
static constexpr int OFF_DXY  = 636 * P;   // 22 planes: per cot [dx, dy] interleaved
static constexpr int OFF_W    = 658 * P;   // packed weights

// packed weight sub-offsets (relative to OFF_W), layout [tap][cin][cout]
static constexpr int PW1 = 0;        // 25*18*24 = 10800
static constexpr int PW2 = 10800;    // 25*24*24 = 14400
static constexpr int PW3 = 25200;
static constexpr int PW4 = 39600;
static constexpr int PW5 = 54000;    // 25*24*12 = 7200
static constexpr int PB4 = 61200;    // transposed+flipped for backward
static constexpr int PB3 = 75600;
static constexpr int PB2 = 90000;
static constexpr int PB1 = 104400;   // 25*24*2 = 1200

// ---------------------------------------------------------------------------
// Repack weights + build the conv5^T one-hot/all-ones cotangent table:
//  forward:  Wp[t][ci][co]  = W[co][ci][t]
//  backward: B [t][co][ci]  = W[co][ci][24-t]   (transpose ci<->co, flip taps)
//  table:    tbl[cot][ci][cy][cx] = sum_{a in A(cy), b in B(cx)} W5[oc(cot)][ci][a][b]
//            cy/cx border classes: 0:gy=0 [0,2], 1:gy=1 [0,3], 2:interior [0,4],
//            3:gy=126 [1,4], 4:gy=127 [2,4]. Same summation order as a direct
//            (a asc, b asc) loop -> bitwise identical to the old bcot_init.
// ---------------------------------------------------------------------------
__global__ void pack_weights(const float* __restrict__ W1, const float* __restrict__ W2,
                             const float* __restrict__ W3, const float* __restrict__ W4,
                             const float* __restrict__ W5, float* __restrict__ wp,
                             float* __restrict__ tbl) {
    int i = blockIdx.x * 256 + threadIdx.x;
    if (i < 10800) {                       // W1p [25][18][24]
        int co = i % 24, ci = (i / 24) % 18, t = i / 432;
        wp[PW1 + i] = W1[(co * 18 + ci) * 25 + t];
    }
    if (i < 14400) {                       // W2p/W3p/W4p + B4/B3/B2
        int co = i % 24, ci = (i / 24) % 24, t = i / 576;
        wp[PW2 + i] = W2[(co * 24 + ci) * 25 + t];
        wp[PW3 + i] = W3[(co * 24 + ci) * 25 + t];
        wp[PW4 + i] = W4[(co * 24 + ci) * 25 + t];
        int cin = i % 24, cout = (i / 24) % 24, tb = i / 576;
        wp[PB4 + i] = W4[(cout * 24 + cin) * 25 + (24 - tb)];
        wp[PB3 + i] = W3[(cout * 24 + cin) * 25 + (24 - tb)];
        wp[PB2 + i] = W2[(cout * 24 + cin) * 25 + (24 - tb)];
    }
    if (i < 7200) {                        // W5p [25][24][12]
        int co = i % 12, ci = (i / 12) % 24, t = i / 288;
        wp[PW5 + i] = W5[(co * 24 + ci) * 25 + t];
    }
    if (i < 1200) {                        // B1 [25][24][2] (only input ch 0,1 needed)
        int ci = i % 2, co = (i / 2) % 24, t = i / 48;
        wp[PB1 + i] = W1[(co * 18 + ci) * 25 + (24 - t)];
    }
    if (i < 6600) {                        // bcot table [11][24][5][5]
        int cx = i % 5, cy = (i / 5) % 5, ci = (i / 25) % 24, cot = i / 600;
        int oc = (cot < 3) ? cot : cot + 1;
        int a0 = (cy <= 2) ? 0 : cy - 2, a1 = (cy >= 2) ? 4 : cy + 2;
        int b0 = (cx <= 2) ? 0 : cx - 2, b1 = (cx >= 2) ? 4 : cx + 2;
        const float* __restrict__ w = W5 + (oc * 24 + ci) * 25;
        float s = 0.f;
        for (int a = a0; a <= a1; ++a)
            for (int b = b0; b <= b1; ++b) s += w[a * 5 + b];
        tbl[i] = s;
    }
}

// Stage x,y,u as a contiguous 18-plane tensor
__global__ void stage_input(const float* __restrict__ x, const float* __restrict__ y,
                            const float* __restrict__ u, float* __restrict__ in18) {
    int i = blockIdx.x * 256 + threadIdx.x;   // 18*P threads
    int pl = i / P, p = i - pl * P;
    float v = (pl == 0) ? x[p] : (pl == 1) ? y[p] : u[(pl - 2) * P + p];
    in18[i] = v;
}

// ---------------------------------------------------------------------------
// Generic 5x5 SAME conv over 128x128 planes.
//  - TH x 16 output tile per TH*16-thread block. TH=16 (forward, 256 thr) or
//    TH=8 (backward, 128 thr -> 2816 blocks for z=22: ~11 blocks/CU; round-6
//    measurement showed occupancy was block-count-limited at 45%).
//  - halo staged in LDS in CIN-chunks; row stride 20 floats -> <=2-way bank
//    aliasing for the 4-rows-per-wave read pattern (free on CDNA4).
//  - weights packed [tap][cin][cout]; inner co loop reads contiguous
//    block-uniform addresses -> scalar loads, SGPR operand in v_fmac.
//  - BATCH: blockIdx.z folds (cotangent, channel-split).
//  - MASK: multiply output by (mask_plane > 0) -> relu backward.
//  - TBL: stage (h4>0 ? border-class table : 0) instead of a materialized
//    cotangent plane (folds old bcot_init into dz3; 'inbase' is h4, unbatched).
// ---------------------------------------------------------------------------
template <int TH, int CIN, int CHUNK, int COUT_TOT, int COB,
          bool RELU, bool MASK, bool BATCH, bool TBL>
__global__ __launch_bounds__(TH * 16, 7) void conv5x5(
    const float* __restrict__ inbase, const float* __restrict__ wp,
    const float* __restrict__ bias, const float* __restrict__ maskbase,
    const float* __restrict__ tbl, float* __restrict__ outbase) {
    constexpr int NSPL = COUT_TOT / COB;
    constexpr int HR = TH + 4;             // halo rows
    constexpr int NT = TH * 16;            // threads
    const int z = blockIdx.z;
    const int half = z % NSPL;
    const int cot = z / NSPL;
    const float* in = inbase + ((BATCH && !TBL) ? cot * CIN * P : 0);
    float* out = outbase + (BATCH ? cot * COUT_TOT * P : 0);
    const int cobase = half * COB;

    __shared__ float smem[CHUNK][HR][20];
    const int tid = threadIdx.x;
    const int bx = blockIdx.x, by = blockIdx.y;
    const int ty = tid >> 4, tx = tid & 15;

    float acc[COB];
#pragma unroll
    for (int co = 0; co < COB; ++co) acc[co] = bias ? bias[cobase + co] : 0.f;

    for (int c0 = 0; c0 < CIN; c0 += CHUNK) {
        if (c0) __syncthreads();           // previous chunk's compute must finish
        for (int i = tid; i < CHUNK * HR * 20; i += NT) {
            int ci = i / (HR * 20), rem = i - ci * (HR * 20);
            int r = rem / 20, c = rem - r * 20;
            int gy = by * TH + r - 2, gx = bx * 16 + c - 2;
            float v = 0.f;
            if ((unsigned)gy < 128u && (unsigned)gx < 128u) {
                if (TBL) {
                    float m = in[(c0 + ci) * P + gy * 128 + gx];
                    if (m > 0.f) {
                        int cy = (gy < 2) ? gy : (gy > 125) ? gy - 123 : 2;
                        int cx = (gx < 2) ? gx : (gx > 125) ? gx - 123 : 2;
                        v = tbl[((cot * CIN + c0 + ci) * 5 + cy) * 5 + cx];
                    }
                } else {
                    v = in[(c0 + ci) * P + gy * 128 + gx];
                }
            }
            smem[ci][r][c] = v;
        }
        __syncthreads();

        for (int a = 0; a < 5; ++a) {
            for (int b = 0; b < 5; ++b) {
                const float* __restrict__ wrow =
                    wp + ((a * 5 + b) * CIN + c0) * COUT_TOT + cobase;
                for (int ci = 0; ci < CHUNK; ++ci) {
                    float v = smem[ci][ty + a][tx + b];
#pragma unroll
                    for (int co = 0; co < COB; ++co)
                        acc[co] = fmaf(v, wrow[ci * COUT_TOT + co], acc[co]);
                }
            }
        }
    }

    const int gy = by * TH + ty, gx = bx * 16 + tx, gp = gy * 128 + gx;
#pragma unroll
    for (int co = 0; co < COB; ++co) {
        float v = acc[co];
        if (RELU) v = v > 0.f ? v : 0.f;
        if (MASK) v = (maskbase[(cobase + co) * P + gp] > 0.f) ? v : 0.f;
        out[(cobase + co) * P + gp] = v;
    }
}

// ---------------------------------------------------------------------------
// Finalize: pde[q] = (kappa_x+v1)*u_rk_x[q] + (kappa_y+v2)*u_rk_y[q] + f
// (second-order terms are exactly zero for a ReLU network), then the two
// 8x8 RK einsums and the 26-plane output concat.
// ---------------------------------------------------------------------------
__global__ __launch_bounds__(256) void finalize(const float* __restrict__ ws,
                                                const float* __restrict__ rkA,
                                                const float* __restrict__ rkb,
                                                float* __restrict__ outp) {
    const int p = blockIdx.x * 256 + threadIdx.x;   // 16384 threads
    const float* o5 = ws + OFF_OUT5;
    const float* dxy = ws + OFF_DXY;

    const float kap = o5[0 * P + p], v1 = o5[1 * P + p];
    const float v2  = o5[2 * P + p], f  = o5[3 * P + p];
    const float kx  = dxy[0 * P + p], ky  = dxy[1 * P + p];
    const float v1x = dxy[2 * P + p], v1y = dxy[3 * P + p];
    const float v2x = dxy[4 * P + p], v2y = dxy[5 * P + p];
    const float cx = kx + v1, cy = ky + v2;

    float pde[8], urk[8];
#pragma unroll
    for (int q = 0; q < 8; ++q) {
        urk[q] = o5[(4 + q) * P + p];
        float ux = dxy[(6 + 2 * q) * P + p];
        float uy = dxy[(7 + 2 * q) * P + p];
        pde[q] = fmaf(cx, ux, fmaf(cy, uy, f));
    }
#pragma unroll
    for (int r = 0; r < 8; ++r) {
        float si = 0.f, sf = 0.f;
#pragma unroll
        for (int j = 0; j < 8; ++j) {
            float a = rkA[r * 8 + j];
            si = fmaf(a, pde[j], si);
            sf = fmaf(a - rkb[j], pde[j], sf);
        }
        outp[r * P + p] = urk[r] + si;
        outp[(8 + r) * P + p] = urk[r] + sf;
    }
    outp[16 * P + p] = kap;
    outp[17 * P + p] = kx;
    outp[18 * P + p] = ky;
    outp[19 * P + p] = v1;
    outp[20 * P + p] = v1x;
    outp[21 * P + p] = v1y;
    outp[22 * P + p] = v2;
    outp[23 * P + p] = v2x;
    outp[24 * P + p] = v2y;
    outp[25 * P + p] = f;
}

extern "C" void kernel_launch(void* const* d_in, const int* in_sizes, int n_in,
                              void* d_out, int out_size, void* d_ws, size_t ws_size,
                              hipStream_t stream) {
    const float* x   = (const float*)d_in[0];
    const float* y   = (const float*)d_in[1];
    const float* u   = (const float*)d_in[2];
    const float* W1  = (const float*)d_in[3];
    const float* b1  = (const float*)d_in[4];
    const float* W2  = (const float*)d_in[5];
    const float* b2  = (const float*)d_in[6];
    const float* W3  = (const float*)d_in[7];
    const float* b3  = (const float*)d_in[8];
    const float* W4  = (const float*)d_in[9];
    const float* b4  = (const float*)d_in[10];
    const float* W5  = (const float*)d_in[11];
    const float* b5  = (const float*)d_in[12];
    const float* rkA = (const float*)d_in[13];
    const float* rkb = (const float*)d_in[14];

    float* ws   = (float*)d_ws;
    float* outp = (float*)d_out;
    float* wp   = ws + OFF_W;
    float* tbl  = ws + OFF_GA;   // table lives in GA; dz3 consumes it before dz2 overwrites GA

    // 1) repack weights (+ bcot border table) + stage 18-channel input
    pack_weights<<<dim3(57), dim3(256), 0, stream>>>(W1, W2, W3, W4, W5, wp, tbl);
    stage_input<<<dim3(18 * 64), dim3(256), 0, stream>>>(x, y, u, ws + OFF_GB);

    // 2) forward net (activations kept for backward relu masks), 16x16 tiles
    dim3 blk256(256), blk128(128);
    conv5x5<16, 18, 9, 24, 4, true, false, false, false><<<dim3(8, 8, 6), blk256, 0, stream>>>(
        ws + OFF_GB, wp + PW1, b1, nullptr, nullptr, ws + OFF_H1);
    conv5x5<16, 24, 12, 24, 4, true, false, false, false><<<dim3(8, 8, 6), blk256, 0, stream>>>(
        ws + OFF_H1, wp + PW2, b2, nullptr, nullptr, ws + OFF_H2);
    conv5x5<16, 24, 12, 24, 4, true, false, false, false><<<dim3(8, 8, 6), blk256, 0, stream>>>(
        ws + OFF_H2, wp + PW3, b3, nullptr, nullptr, ws + OFF_H3);
    conv5x5<16, 24, 12, 24, 4, true, false, false, false><<<dim3(8, 8, 6), blk256, 0, stream>>>(
        ws + OFF_H3, wp + PW4, b4, nullptr, nullptr, ws + OFF_H4);
    conv5x5<16, 24, 12, 12, 4, false, false, false, false><<<dim3(8, 8, 3), blk256, 0, stream>>>(
        ws + OFF_H4, wp + PW5, b5, nullptr, nullptr, ws + OFF_OUT5);

    // 3) backward: 11 one-hot cotangents batched in blockIdx.z, 8x16 tiles.
    // dz3 = m3 * (W4^T (*) [m4 * conv5T-table]) — bcot_init folded in via TBL.
    conv5x5<8, 24, 12, 24, 12, false, true, true, true><<<dim3(8, 16, 22), blk128, 0, stream>>>(
        ws + OFF_H4, wp + PB4, nullptr, ws + OFF_H3, tbl, ws + OFF_GB);
    // dz2
    conv5x5<8, 24, 12, 24, 12, false, true, true, false><<<dim3(8, 16, 22), blk128, 0, stream>>>(
        ws + OFF_GB, wp + PB3, nullptr, ws + OFF_H2, nullptr, ws + OFF_GA);
    // dz1
    conv5x5<8, 24, 12, 24, 12, false, true, true, false><<<dim3(8, 16, 22), blk128, 0, stream>>>(
        ws + OFF_GA, wp + PB2, nullptr, ws + OFF_H1, nullptr, ws + OFF_GB);
    // dL/d(x,y): conv1^T restricted to input channels {0,1}
    conv5x5<8, 24, 12, 2, 2, false, false, true, false><<<dim3(8, 16, 11), blk128, 0, stream>>>(
        ws + OFF_GB, wp + PB1, nullptr, nullptr, nullptr, ws + OFF_DXY);

    // 4) pointwise PDE + RK combine + output concat (26 planes)
    finalize<<<dim3(64), blk256, 0, stream>>>(ws, rkA, rkb, outp);
}